// Round 7
// baseline (2388.296 us; speedup 1.0000x reference)
//
#include <hip/hip_runtime.h>

typedef unsigned short u16;
typedef __attribute__((ext_vector_type(8))) short short8;
typedef __attribute__((ext_vector_type(4))) float float4v;

typedef __attribute__((address_space(3))) unsigned int lds_u32;
typedef __attribute__((address_space(1))) unsigned int glb_u32;

__device__ __forceinline__ void gld16(const void* g, void* l) {
    __builtin_amdgcn_global_load_lds((const glb_u32*)g, (lds_u32*)l, 16, 0, 0);
}

__device__ __forceinline__ u16 f2bf(float f) {
    union { float f; unsigned u; } x;
    x.f = f;
    unsigned r = x.u + 0x7FFFu + ((x.u >> 16) & 1u);
    return (u16)(r >> 16);
}

// monotone u16 key of a similarity in [-1,1]; step 3.05e-5 (< bf16 screen noise)
__device__ __forceinline__ u16 simkey(float v) {
    int k = (int)((v + 1.0f) * 32768.0f);
    k = k < 0 ? 0 : (k > 65535 ? 65535 : k);
    return (u16)k;
}

// ---------------------------------------------------------------------------
// Per-row L2 norm + normalized bf16 cast (emb). One block / row, D=2048.
// ---------------------------------------------------------------------------
__global__ __launch_bounds__(256)
void rownorm_cast(const float* __restrict__ src, u16* __restrict__ dst,
                  double* __restrict__ invn)
{
    constexpr int D = 2048;
    __shared__ double red[256];
    __shared__ double invs;
    const int row = blockIdx.x;
    const int t = threadIdx.x;
    const float* sr = src + (size_t)row * D;
    float x[8];
    double ss = 0.0;
#pragma unroll
    for (int i = 0; i < 8; ++i) {
        x[i] = sr[t + i * 256];
        ss += (double)x[i] * (double)x[i];
    }
    red[t] = ss;
    __syncthreads();
    for (int s = 128; s > 0; s >>= 1) {
        if (t < s) red[t] += red[t + s];
        __syncthreads();
    }
    if (t == 0) {
        double n = sqrt(red[0]);
        double inv = 1.0 / fmax(n, 1e-12);
        invs = inv;
        invn[row] = inv;
    }
    __syncthreads();
    float inv = (float)invs;
    u16* dr = dst + (size_t)row * D;
#pragma unroll
    for (int i = 0; i < 8; ++i) dr[t + i * 256] = f2bf(x[i] * inv);
}

// ---------------------------------------------------------------------------
// Per-row L2 norm only (voc): writes double + float inverse norms.
// ---------------------------------------------------------------------------
__global__ __launch_bounds__(256)
void rownorm_only(const float* __restrict__ src, double* __restrict__ invn,
                  float* __restrict__ invnf)
{
    constexpr int D = 2048;
    __shared__ double red[256];
    const int row = blockIdx.x;
    const int t = threadIdx.x;
    const float* sr = src + (size_t)row * D;
    double ss = 0.0;
#pragma unroll
    for (int i = 0; i < 8; ++i) {
        float v = sr[t + i * 256];
        ss += (double)v * (double)v;
    }
    red[t] = ss;
    __syncthreads();
    for (int s = 128; s > 0; s >>= 1) {
        if (t < s) red[t] += red[t + s];
        __syncthreads();
    }
    if (t == 0) {
        double n = sqrt(red[0]);
        double inv = 1.0 / fmax(n, 1e-12);
        invn[row] = inv;
        invnf[row] = (float)inv;
    }
}

// ---------------------------------------------------------------------------
// Precast a block of vocab rows to normalized bf16 (chunk-local layout).
// ---------------------------------------------------------------------------
__global__ __launch_bounds__(256)
void precast_rows(const float* __restrict__ Bf, const float* __restrict__ invBf,
                  u16* __restrict__ Bbf, int colBase)
{
    const int t = threadIdx.x;
    const int v = colBase + blockIdx.x;
    float s = invBf[v];
    const float* src = Bf + (size_t)v * 2048 + t * 8;
    float4v x0 = *(const float4v*)src;
    float4v x1 = *(const float4v*)(src + 4);
    short8 pk;
    pk[0] = (short)f2bf(x0[0] * s); pk[1] = (short)f2bf(x0[1] * s);
    pk[2] = (short)f2bf(x0[2] * s); pk[3] = (short)f2bf(x0[3] * s);
    pk[4] = (short)f2bf(x1[0] * s); pk[5] = (short)f2bf(x1[1] * s);
    pk[6] = (short)f2bf(x1[2] * s); pk[7] = (short)f2bf(x1[3] * s);
    *(short8*)(Bbf + (size_t)blockIdx.x * 2048 + t * 8) = pk;
}

// ---------------------------------------------------------------------------
// 256x192 bf16 GEMM, 8 waves (2Mx4N), BK=64, 8-PHASE fine interleave
// (4 phases/K-tile: ks x mi-half quadrants, 12 MFMA each). Each phase:
//   {ds_reads ; 1 A-stage gld16 ; s_barrier ; lgkmcnt(0)+sched_barrier ;
//    setprio(1) ; 12 MFMA ; setprio(0) ; s_barrier}   (m201 skeleton)
// A uses a 3-slot LDS ring (96 KB) so A(t+2) pieces stream in DURING the
// compute of tile t (target slot = (t+2)%3 holds t-1, dead since the t-1
// boundary). B uses a 2-ring (48 KB), staged at the tile boundary (its slot
// is dead after phase 4's lgkm(0)+barrier). Boundary wait is counted:
// vmcnt(7) = A(t+2) 4 + B(t+2) 3 allowed in flight => tile t+1 landed
// (vmcnt retires in order). XOR bank-swizzle (T2) global-side + read-side;
// row&7 == lr&7 holds (all row offsets are multiples of 8/16/48).
// Grid 32x8 = 256 blocks = 1/CU. ldc = 1536 always (pad masked in top8).
// ---------------------------------------------------------------------------
__global__ __launch_bounds__(512, 2)
void gemm256_bt_u16(const u16* __restrict__ A, const u16* __restrict__ B,
                    u16* __restrict__ Csim, int ldc)
{
    constexpr int Kdim = 2048;
    constexpr int NT = Kdim / 64;            // 32 K-tiles
    __shared__ __align__(16) u16 As[3][256 * 64];   // 96 KB (3-ring)
    __shared__ __align__(16) u16 Bs[2][192 * 64];   // 48 KB (2-ring)
    const int tid = threadIdx.x;
    const int lane = tid & 63;
    const int wave = tid >> 6;
    const int bx = blockIdx.x & 31;          // 32 row tiles
    const int by = blockIdx.x >> 5;          // 8 col tiles
    const int rowTile = bx * 256;
    const int colTile = by * 192;
    const u16* Ab = A + (size_t)rowTile * Kdim;
    const u16* Bb = B + (size_t)colTile * Kdim;

    const int wr = (wave >> 2) * 128;        // wave row offset (0,128)
    const int wc = (wave & 3) * 48;          // wave col offset (0,48,96,144)
    const int lr = lane & 15;
    const int lq = lane >> 4;

    float4v acc[8][3];
#pragma unroll
    for (int i = 0; i < 8; ++i)
#pragma unroll
        for (int j = 0; j < 3; ++j) acc[i][j] = (float4v){0.f, 0.f, 0.f, 0.f};

    // A-stage piece p of tile t2 into ring slot: 512 chunks (1 gld16/thread).
    // chunk c -> row r=c>>3, slot s=c&7; LDS linear, global pre-swizzled.
    auto stageApiece = [&](int t2, int slot, int p) {
        int c = p * 512 + tid;
        int r = c >> 3, s = c & 7;
        gld16(Ab + (size_t)r * Kdim + t2 * 64 + ((s ^ (r & 7)) * 8),
              &As[slot][c * 8]);
    };
    // B-stage of tile t2 (3 gld16/thread).
    auto stageB = [&](int t2, int b) {
#pragma unroll
        for (int i = 0; i < 3; ++i) {
            int c = i * 512 + tid;
            int r = c >> 3, s = c & 7;
            gld16(Bb + (size_t)r * Kdim + t2 * 64 + ((s ^ (r & 7)) * 8),
                  &Bs[b][c * 8]);
        }
    };

    // prologue: tiles 0,1 fully staged; wait tile 0 (allow tile 1's 7 loads)
#pragma unroll
    for (int p = 0; p < 4; ++p) stageApiece(0, 0, p);
    stageB(0, 0);
#pragma unroll
    for (int p = 0; p < 4; ++p) stageApiece(1, 1, p);
    stageB(1, 1);
    asm volatile("s_waitcnt vmcnt(7)" ::: "memory");
    __builtin_amdgcn_sched_barrier(0);
    __builtin_amdgcn_s_barrier();
    __builtin_amdgcn_sched_barrier(0);

#define PHASE(KS, MIH, PIECE, READ_B)                                          \
    {                                                                          \
        short8 af[4];                                                          \
        _Pragma("unroll")                                                      \
        for (int mi = 0; mi < 4; ++mi) {                                       \
            int r = wr + ((MIH) * 4 + mi) * 16 + lr;                           \
            int s = ((KS) * 4 + lq) ^ (lr & 7);                                \
            af[mi] = *(const short8*)&Acur[r * 64 + s * 8];                    \
        }                                                                      \
        if (READ_B) {                                                          \
            _Pragma("unroll")                                                  \
            for (int ni = 0; ni < 3; ++ni) {                                   \
                int r = wc + ni * 16 + lr;                                     \
                int s = ((KS) * 4 + lq) ^ (lr & 7);                            \
                bfr[ni] = *(const short8*)&Bcur[r * 64 + s * 8];               \
            }                                                                  \
        }                                                                      \
        if (pf) stageApiece(t + 2, sA2, (PIECE));                              \
        __builtin_amdgcn_s_barrier();                                          \
        asm volatile("s_waitcnt lgkmcnt(0)" ::: "memory");                     \
        __builtin_amdgcn_sched_barrier(0);                                     \
        __builtin_amdgcn_s_setprio(1);                                         \
        _Pragma("unroll")                                                      \
        for (int mi = 0; mi < 4; ++mi)                                         \
            _Pragma("unroll")                                                  \
            for (int ni = 0; ni < 3; ++ni)                                     \
                acc[(MIH) * 4 + mi][ni] =                                      \
                    __builtin_amdgcn_mfma_f32_16x16x32_bf16(                   \
                        af[mi], bfr[ni], acc[(MIH) * 4 + mi][ni], 0, 0, 0);    \
        __builtin_amdgcn_s_setprio(0);                                         \
        __builtin_amdgcn_s_barrier();                                          \
        __builtin_amdgcn_sched_barrier(0);                                     \
    }

    for (int t = 0; t < NT; ++t) {
        const u16* Acur = &As[t % 3][0];
        const u16* Bcur = &Bs[t & 1][0];
        const int sA2 = (t + 2) % 3;
        const bool pf = (t + 2 < NT);
        short8 bfr[3];

        PHASE(0, 0, 0, 1)   // ks0, mi 0-3, + B ks0
        PHASE(0, 1, 1, 0)   // ks0, mi 4-7
        PHASE(1, 0, 2, 1)   // ks1, mi 0-3, + B ks1
        PHASE(1, 1, 3, 0)   // ks1, mi 4-7

        // boundary: B slot (t&1) dead (phase-4 lgkm+barrier) -> stage t+2
        if (pf) {
            stageB(t + 2, t & 1);
            asm volatile("s_waitcnt vmcnt(7)" ::: "memory");  // t+1 landed
        } else {
            asm volatile("s_waitcnt vmcnt(0)" ::: "memory");  // drain tail
        }
        __builtin_amdgcn_sched_barrier(0);
        __builtin_amdgcn_s_barrier();
        __builtin_amdgcn_sched_barrier(0);
    }
#undef PHASE

    // C/D layout: col = lane&15, row = (lane>>4)*4 + reg
#pragma unroll
    for (int mi = 0; mi < 8; ++mi) {
#pragma unroll
        for (int r = 0; r < 4; ++r) {
            int row = rowTile + wr + mi * 16 + lq * 4 + r;
            u16* crow = Csim + (size_t)row * ldc + colTile + wc + lr;
#pragma unroll
            for (int ni = 0; ni < 3; ++ni) crow[ni * 16] = simkey(acc[mi][ni][r]);
        }
    }
}

// ---------------------------------------------------------------------------
// Per-row top-8: one wave per row (4 rows/block, zero barriers, zero LDS).
// Packed key|idx int -> single __shfl_xor butterfly per pass. Row stride is
// ldc (1536); only j < cols participate (pad columns masked). Fold: blocks
// 0..nextCols-1 also stage next chunk's bf16 B rows. grid = N/4.
// ---------------------------------------------------------------------------
__global__ __launch_bounds__(256)
void top8_merge_u16(const u16* __restrict__ sims, int ldc, int cols, int colBase,
                    int* __restrict__ candK, int* __restrict__ candI, int isFirst,
                    const float* __restrict__ Bf, const float* __restrict__ invBf,
                    u16* __restrict__ Bbf, int nextBase, int nextCols)
{
    const int t = threadIdx.x;

    // fold: stage next chunk's normalized-bf16 B rows (uniform per block)
    if (blockIdx.x < nextCols) {
        int v = nextBase + blockIdx.x;
        float s = invBf[v];
        const float* src = Bf + (size_t)v * 2048 + t * 8;
        float4v x0 = *(const float4v*)src;
        float4v x1 = *(const float4v*)(src + 4);
        short8 pks;
        pks[0] = (short)f2bf(x0[0] * s); pks[1] = (short)f2bf(x0[1] * s);
        pks[2] = (short)f2bf(x0[2] * s); pks[3] = (short)f2bf(x0[3] * s);
        pks[4] = (short)f2bf(x1[0] * s); pks[5] = (short)f2bf(x1[1] * s);
        pks[6] = (short)f2bf(x1[2] * s); pks[7] = (short)f2bf(x1[3] * s);
        *(short8*)(Bbf + (size_t)blockIdx.x * 2048 + t * 8) = pks;
    }

    const int lane = t & 63;
    const int wave = t >> 6;
    const int row = blockIdx.x * 4 + wave;
    const u16* srow = sims + (size_t)row * ldc;

    // load 24 keys/lane via 3 x short8 (16B aligned); mask j >= cols to -1
    int pk[24];
#pragma unroll
    for (int i = 0; i < 3; ++i) {
        short8 v = *(const short8*)(srow + i * 512 + lane * 8);
#pragma unroll
        for (int e = 0; e < 8; ++e) {
            int j = i * 512 + lane * 8 + e;
            int key = (int)(u16)v[e];
            pk[i * 8 + e] = (j < cols) ? ((key << 11) | (2047 - j)) : -1;
        }
    }

    int best[8];
#pragma unroll
    for (int p = 0; p < 8; ++p) {
        int bv = -1;
#pragma unroll
        for (int i = 0; i < 24; ++i) bv = pk[i] > bv ? pk[i] : bv;
#pragma unroll
        for (int off = 32; off > 0; off >>= 1) {
            int ov = __shfl_xor(bv, off);
            bv = ov > bv ? ov : bv;
        }
        best[p] = bv;                       // all lanes agree
        int cj = 2047 - (bv & 2047);        // winning column (chunk-local)
#pragma unroll
        for (int i = 0; i < 3; ++i)
#pragma unroll
            for (int e = 0; e < 8; ++e)
                if (i * 512 + lane * 8 + e == cj) pk[i * 8 + e] = -1;
    }

    if (lane == 0) {
        int bK[8], bI[8];
#pragma unroll
        for (int p = 0; p < 8; ++p) {
            bK[p] = best[p] >> 11;
            bI[p] = colBase + (2047 - (best[p] & 2047));
        }
        if (isFirst) {
            for (int i = 0; i < 8; ++i) {
                candK[row * 8 + i] = bK[i];
                candI[row * 8 + i] = bI[i];
            }
        } else {
            int oK[8], oI[8], nK[8], nI[8];
            for (int i = 0; i < 8; ++i) { oK[i] = candK[row * 8 + i]; oI[i] = candI[row * 8 + i]; }
            int a = 0, b = 0;
            for (int i = 0; i < 8; ++i) {
                if (oK[a] >= bK[b]) { nK[i] = oK[a]; nI[i] = oI[a]; ++a; }  // old idx lower
                else { nK[i] = bK[b]; nI[i] = bI[b]; ++b; }
            }
            for (int i = 0; i < 8; ++i) { candK[row * 8 + i] = nK[i]; candI[row * 8 + i] = nI[i]; }
        }
    }
}

// ---------------------------------------------------------------------------
// fp64 rescore of 8 candidates (rows cached in LDS), exact top-5, softmax,
// blend, write. One block / row.
// ---------------------------------------------------------------------------
__global__ __launch_bounds__(256)
void finalize_kernel(const float* __restrict__ emb, const float* __restrict__ voc,
                     const double* __restrict__ invA, const double* __restrict__ invB,
                     const int* __restrict__ candI, float* __restrict__ out)
{
    constexpr int D = 2048;
    __shared__ float rows8[8][D];    // 64 KB
    __shared__ float erow[D];        // 8 KB
    __shared__ double wred[4][8];
    __shared__ double s8[8];
    __shared__ int i8[8];
    __shared__ float w5[5];
    __shared__ int slot5[5];
    const int row = blockIdx.x;
    const int t = threadIdx.x;
    const int lane = t & 63;
    const int wave = t >> 6;

    if (t < 8) i8[t] = candI[row * 8 + t];
    __syncthreads();
    {
        const float4v* er = (const float4v*)(emb + (size_t)row * D);
        float4v* ed = (float4v*)erow;
        ed[t] = er[t];
        ed[t + 256] = er[t + 256];
#pragma unroll
        for (int k = 0; k < 8; ++k) {
            const float4v* src = (const float4v*)(voc + (size_t)i8[k] * D);
            float4v* dst = (float4v*)rows8[k];
            dst[t] = src[t];
            dst[t + 256] = src[t + 256];
        }
    }
    __syncthreads();

    double part[8] = {0, 0, 0, 0, 0, 0, 0, 0};
#pragma unroll
    for (int i = 0; i < 8; ++i) {
        int d = t + i * 256;
        double e = (double)erow[d];
#pragma unroll
        for (int k = 0; k < 8; ++k) part[k] += e * (double)rows8[k][d];
    }
#pragma unroll
    for (int k = 0; k < 8; ++k) {
#pragma unroll
        for (int off = 32; off > 0; off >>= 1) part[k] += __shfl_down(part[k], off);
        if (lane == 0) wred[wave][k] = part[k];
    }
    __syncthreads();
    if (t < 8) {
        double sum = wred[0][t] + wred[1][t] + wred[2][t] + wred[3][t];
        s8[t] = sum * invA[row] * invB[i8[t]];
    }
    __syncthreads();
    if (t == 0) {
        int ord[8] = {0, 1, 2, 3, 4, 5, 6, 7};
        for (int a = 0; a < 5; ++a) {
            int best = a;
            for (int b = a + 1; b < 8; ++b) {
                if (s8[ord[b]] > s8[ord[best]] ||
                    (s8[ord[b]] == s8[ord[best]] && i8[ord[b]] < i8[ord[best]]))
                    best = b;
            }
            int tmp = ord[a]; ord[a] = ord[best]; ord[best] = tmp;
        }
        double m = s8[ord[0]];
        double e[5], sum = 0.0;
        for (int k = 0; k < 5; ++k) { e[k] = exp((s8[ord[k]] - m) * 10.0); sum += e[k]; }
        for (int k = 0; k < 5; ++k) {
            w5[k] = (float)(e[k] / sum);
            slot5[k] = ord[k];
        }
    }
    __syncthreads();
    float q0 = w5[0], q1 = w5[1], q2 = w5[2], q3 = w5[3], q4 = w5[4];
    int s0 = slot5[0], s1 = slot5[1], s2 = slot5[2], s3 = slot5[3], s4 = slot5[4];
    float* orow = out + (size_t)row * D;
#pragma unroll
    for (int i = 0; i < 8; ++i) {
        int d = t + i * 256;
        float p = q0 * rows8[s0][d] + q1 * rows8[s1][d] + q2 * rows8[s2][d] +
                  q3 * rows8[s3][d] + q4 * rows8[s4][d];
        orow[d] = 0.5f * erow[d] + 0.5f * p;
    }
}

// ---------------------------------------------------------------------------
extern "C" void kernel_launch(void* const* d_in, const int* in_sizes, int n_in,
                              void* d_out, int out_size, void* d_ws, size_t ws_size,
                              hipStream_t stream)
{
    (void)in_sizes; (void)n_in; (void)out_size; (void)ws_size;
    constexpr int N = 8192, V = 32000;
    constexpr int CHUNK = 1536;              // 8 x 192; last chunk 1280 padded to 1536
    constexpr int NCHUNK = 21;               // 20*1536 + 1280 = 32000
    const float* emb = (const float*)d_in[0];
    const float* voc = (const float*)d_in[1];
    float* out = (float*)d_out;
    char* ws = (char*)d_ws;

    // d_ws layout — TOTAL 973,824 bytes (<1 MB, proven safe):
    double* invA  = (double*)(ws);           // 65,536
    double* invB  = (double*)(ws + 65536);   // 256,000
    float*  invBf = (float*)(ws + 321536);   // 128,000
    int*    candK = (int*)(ws + 449536);     // 262,144
    int*    candI = (int*)(ws + 711680);     // 262,144

    // d_out (67,108,864 B) as scratch until finalize overwrites it:
    //   Abf      u16[8192*2048]   @ 0           (33,554,432)
    //   simsU16  u16[8192*1536]   @ 33,554,432  (25,165,824)
    //   BbfChunk u16[1536*2048]   @ 58,720,256  ( 6,291,456)  -> total 65,011,712
    u16* Abf  = (u16*)d_out;
    u16* sims = (u16*)((char*)d_out + 33554432);
    u16* Bbf  = (u16*)((char*)d_out + 58720256);

    rownorm_cast<<<N, 256, 0, stream>>>(emb, Abf, invA);
    rownorm_only<<<V, 256, 0, stream>>>(voc, invB, invBf);
    precast_rows<<<CHUNK, 256, 0, stream>>>(voc, invBf, Bbf, 0);

    for (int c = 0; c < NCHUNK; ++c) {
        int colBase = c * CHUNK;
        int cols = (c == NCHUNK - 1) ? (V - colBase) : CHUNK;   // 1536 or 1280
        int nextBase = colBase + CHUNK;
        int nextCols = (c < NCHUNK - 1)
                           ? ((c + 1 == NCHUNK - 1) ? (V - nextBase) : CHUNK)
                           : 0;
        // GEMM always computes the full padded 1536 cols: 32 x 8 = 256 blocks
        // (exactly one per CU). Pad B rows are stale-but-valid; top8 masks.
        gemm256_bt_u16<<<dim3(256), 512, 0, stream>>>(Abf, Bbf, sims, CHUNK);
        top8_merge_u16<<<N / 4, 256, 0, stream>>>(sims, CHUNK, cols, colBase,
                                                  candK, candI, c == 0, voc,
                                                  invBf, Bbf, nextBase, nextCols);
    }

    finalize_kernel<<<N, 256, 0, stream>>>(emb, voc, invA, invB, candI, out);
}